// Round 3
// baseline (3056.566 us; speedup 1.0000x reference)
//
#include <hip/hip_runtime.h>
#include <hip/hip_bf16.h>

// LSTM B=64, T=256, ID=512, HD=1024. Gates F,I,A,O.
// Round 7 (2nd resubmit — rounds 1-2 hit GPUAcquisitionTimeout, no data):
//  (1) Wh fragments pinned in AGPRs via "+a" asm constraint (round 6's "+v"
//      pin was spilled: VGPR_Count stayed 156 < the 256 regs awh needs).
//      gfx950 MFMA reads srcA straight from AGPR -> zero per-step Wh traffic.
//  (2) Flags packed to [wave][blk] ints: poll = ONE coalesced dwordx2 load
//      (8 lines) instead of 2x 64-line divergent gathers per iteration.
//  (3) gates3 (gx) double-buffered one step ahead, issued AFTER flag publish;
//      out stores moved after flag publish. The pre-flag vmcnt(0) drain now
//      covers only the packed h-store ack to MALL.
//  (4) All 32 h B-fragments issued up-front (regs freed by AGPR move), MFMA
//      runs as 4 independent accumulate chains.

#define B_  64
#define T_  256
#define ID_ 512
#define HD_ 1024
#define NG_ 4096
#define M1_ (B_ * T_)
#define NBLK 128
#define UPB  8

typedef __bf16 bf16x8 __attribute__((ext_vector_type(8)));
typedef float  f32x4  __attribute__((ext_vector_type(4)));
typedef int    i32x4  __attribute__((ext_vector_type(4)));
typedef int    i32x2  __attribute__((ext_vector_type(2)));
typedef short  s16x4  __attribute__((ext_vector_type(4)));

using bf16 = __hip_bfloat16;

__device__ __forceinline__ float sigmoid_fast(float x) {
    return 1.0f / (1.0f + __expf(-x));
}
__device__ __forceinline__ float tanh_fast(float x) {
    return 1.0f - 2.0f / (__expf(2.0f * x) + 1.0f);
}
__device__ __forceinline__ unsigned short bf16_bits(float x) {
    union { bf16 h; unsigned short u; } cv;
    cv.h = __float2bfloat16(x);
    return cv.u;
}
__device__ __forceinline__ bf16x8 vload8(const bf16* p) {
    union { i32x4 i; bf16x8 h; } cv;
    cv.i = *reinterpret_cast<const volatile i32x4*>(p);
    return cv.h;
}
__device__ __forceinline__ bf16x8 as_bf16x8(i32x4 v) {
    union { i32x4 i; bf16x8 h; } cv;
    cv.i = v;
    return cv.h;
}

// ---------------------------------------------------------------- prep ----
__global__ __launch_bounds__(256) void prep_kernel(
    const float* __restrict__ x, const float* __restrict__ Wi,
    const float* __restrict__ Wh, bf16* __restrict__ xb,
    bf16* __restrict__ wiT, bf16* __restrict__ whT,
    bf16* __restrict__ hbuf, int* __restrict__ flags) {
    const int tid = blockIdx.x * 256 + threadIdx.x;  // [0, 2097152)

    if (tid < NBLK * 4 * 16) flags[tid] = 0;          // covers packed flags
    if (tid < (B_ * HD_) / 4)                         // h[-1] = 0 (buf0)
        *reinterpret_cast<s16x4*>(hbuf + (size_t)tid * 4) = s16x4{0, 0, 0, 0};

    const float4 v = reinterpret_cast<const float4*>(x)[tid];
    bf16 tmp[4] = { __float2bfloat16(v.x), __float2bfloat16(v.y),
                    __float2bfloat16(v.z), __float2bfloat16(v.w) };
    *reinterpret_cast<s16x4*>(xb + 4 * (size_t)tid) =
        *reinterpret_cast<s16x4*>(tmp);

    {   // WiT[n][k] = Wi[k][n]
        const int n = tid >> 9, k = tid & 511;
        wiT[tid] = __float2bfloat16(Wi[(size_t)k * NG_ + n]);
    }
    for (int e = 0; e < 2; ++e) {  // WhT[n][k] = Wh[k][n]
        const int idx = 2 * tid + e;
        const int n = idx >> 10, k = idx & 1023;
        whT[idx] = __float2bfloat16(Wh[(size_t)k * NG_ + n]);
    }
}

// ---------------------------------------------------- phase-1 gates GEMM ----
// gates3 layout: [t][blk][tid(256)][8] bf16, e = nt*4+r in step-MFMA acc order.
__global__ __launch_bounds__(256) void gates_gemm_kernel(
    const bf16* __restrict__ xb, const bf16* __restrict__ wiT,
    const float* __restrict__ bi, const float* __restrict__ bh,
    bf16* __restrict__ gates3) {
    __shared__ __align__(16) bf16 As[128 * 40];
    __shared__ __align__(16) bf16 Bs[128 * 40];
    const int tid  = threadIdx.x;
    const int lane = tid & 63, wave = tid >> 6;
    const int wm = wave >> 1, wn = wave & 1;
    const int l15 = lane & 15, quad = lane >> 4;
    const int row0 = blockIdx.x * 128, col0 = blockIdx.y * 128;

    f32x4 acc[4][4];
    for (int i = 0; i < 4; ++i)
        for (int j = 0; j < 4; ++j) acc[i][j] = f32x4{0.f, 0.f, 0.f, 0.f};

    for (int kt = 0; kt < ID_ / 32; ++kt) {
        const int k0 = kt * 32;
        for (int L = tid; L < 512; L += 256) {
            const int r = L >> 2, s = L & 3;
            *reinterpret_cast<i32x4*>(&As[r * 40 + s * 8]) =
                *reinterpret_cast<const i32x4*>(xb + (size_t)(row0 + r) * ID_ + k0 + s * 8);
            *reinterpret_cast<i32x4*>(&Bs[r * 40 + s * 8]) =
                *reinterpret_cast<const i32x4*>(wiT + (size_t)(col0 + r) * ID_ + k0 + s * 8);
        }
        __syncthreads();
        bf16x8 af[4], bfv[4];
        for (int mt = 0; mt < 4; ++mt)
            af[mt] = *reinterpret_cast<const bf16x8*>(
                &As[(wm * 64 + mt * 16 + l15) * 40 + quad * 8]);
        for (int nt = 0; nt < 4; ++nt)
            bfv[nt] = *reinterpret_cast<const bf16x8*>(
                &Bs[(wn * 64 + nt * 16 + l15) * 40 + quad * 8]);
        for (int mt = 0; mt < 4; ++mt)
            for (int nt = 0; nt < 4; ++nt)
                acc[mt][nt] = __builtin_amdgcn_mfma_f32_16x16x32_bf16(
                    af[mt], bfv[nt], acc[mt][nt], 0, 0, 0);
        __syncthreads();
    }
    // epilogue: +(bi+bh), store to gates3 in persistent-kernel acc order
    for (int mt = 0; mt < 4; ++mt) {
        for (int nt = 0; nt < 4; ++nt) {
            const int cg = col0 + wn * 64 + nt * 16 + l15;
            const int g = cg >> 10, u = cg & 1023;
            const int blk = u >> 3, jl = u & 7;
            const int lcol = g * 8 + jl;               // m-index in step MFMA
            const int nt2 = lcol >> 4, q2 = (lcol >> 2) & 3, r2 = lcol & 3;
            const int e = nt2 * 4 + r2;
            const float bias = bi[cg] + bh[cg];
            for (int r = 0; r < 4; ++r) {
                const int rg = row0 + wm * 64 + mt * 16 + quad * 4 + r;
                const int b = rg >> 8, t = rg & 255;   // row = b*T + t
                const int tid2 = (b >> 4) * 64 + q2 * 16 + (b & 15);
                gates3[(((size_t)t * NBLK + blk) * 256 + tid2) * 8 + e] =
                    __float2bfloat16(acc[mt][nt][r] + bias);
            }
        }
    }
}

// ------------------------------------------------- persistent LSTM steps ----
__global__ __launch_bounds__(256, 1) void lstm_persistent_kernel(
    const bf16* __restrict__ gates3, const bf16* __restrict__ whT,
    bf16* __restrict__ hbuf, float* __restrict__ out, int* __restrict__ flags) {
    const int tid  = threadIdx.x;
    const int lane = tid & 63, w = tid >> 6;
    const int l15 = lane & 15, quad = lane >> 4;
    const int blk = blockIdx.x;                 // hidden units [blk*8, blk*8+8)

    // ---- preload Wh A-fragments and PIN them in AGPRs ----
    // A[m=lcol][k]: lcol = nt*16 + l15 -> whT row (lcol>>3)*HD + blk*8 + (lcol&7)
    i32x4 awh0[32], awh1[32];
    {
        const int lcol0 = l15;
        const int lcol1 = 16 + l15;
        const size_t wrow0 = (size_t)((lcol0 >> 3) * HD_ + blk * UPB + (lcol0 & 7));
        const size_t wrow1 = (size_t)((lcol1 >> 3) * HD_ + blk * UPB + (lcol1 & 7));
#pragma unroll
        for (int kk = 0; kk < 32; ++kk) {
            awh0[kk] = *reinterpret_cast<const i32x4*>(
                whT + wrow0 * HD_ + kk * 32 + quad * 8);
            awh1[kk] = *reinterpret_cast<const i32x4*>(
                whT + wrow1 * HD_ + kk * 32 + quad * 8);
        }
    }
    // force residency in the AGPR file (256 a-regs; unified RF has room at
    // 1 wave/SIMD). MFMA srcA reads AGPR directly on gfx950.
#pragma unroll
    for (int kk = 0; kk < 32; ++kk) {
        asm volatile("" : "+a"(awh0[kk]));
        asm volatile("" : "+a"(awh1[kk]));
    }

    // cell-update map (after shfl_xor(32) pairing quad<->quad^2):
    // thread covers (b = w*16+l15, units jl0, jl0+1)
    const int jl0 = 4 * (quad & 1) + 2 * (quad >> 1);
    const int b = w * 16 + l15;
    float c0 = 0.f, c1 = 0.f;

    // packed flags: flags[w*128 + blk]. Consumer lane polls blocks
    // 2*lane, 2*lane+1 of its own wave with a single dwordx2 load.
    const int* pollp = flags + (w << 7) + (lane << 1);

    // gx double-buffer: prefetch step 0 now; inside the loop step t+1 is
    // issued AFTER the flag publish so the pre-flag vmcnt(0) never waits
    // on an HBM load.
    bf16x8 gx_next = *reinterpret_cast<const bf16x8*>(
        gates3 + ((size_t)blk * 256 + tid) * 8);

    for (int t = 0; t < T_; ++t) {
        const bf16* hin  = hbuf + (size_t)(t & 1) * (B_ * HD_);
        bf16*       hout = hbuf + (size_t)((t + 1) & 1) * (B_ * HD_);
        const bf16x8 gx = gx_next;

        // wait until all blocks' wave w published h[t-1]
        if (t > 0) {
            for (;;) {
                i32x2 f = *reinterpret_cast<const volatile i32x2*>(pollp);
                if (f.x >= t && f.y >= t) break;
                __builtin_amdgcn_s_sleep(1);
            }
        }
        __asm__ __volatile__("" ::: "memory");   // no load hoisting above poll

        // ---- B-frags straight from global (volatile -> MALL), all 32 up
        //      front: pay MALL latency once, MFMAs pipeline on the returns.
        const bf16* hb_base = hin + (size_t)b * HD_ + quad * 8;
        bf16x8 hb[32];
#pragma unroll
        for (int kk = 0; kk < 32; ++kk)
            hb[kk] = vload8(hb_base + kk * 32);

        f32x4 a0e = f32x4{0.f, 0.f, 0.f, 0.f};
        f32x4 a0o = f32x4{0.f, 0.f, 0.f, 0.f};
        f32x4 a1e = f32x4{0.f, 0.f, 0.f, 0.f};
        f32x4 a1o = f32x4{0.f, 0.f, 0.f, 0.f};
#pragma unroll
        for (int kk = 0; kk < 32; kk += 2) {
            a0e = __builtin_amdgcn_mfma_f32_16x16x32_bf16(
                as_bf16x8(awh0[kk]), hb[kk], a0e, 0, 0, 0);
            a1e = __builtin_amdgcn_mfma_f32_16x16x32_bf16(
                as_bf16x8(awh1[kk]), hb[kk], a1e, 0, 0, 0);
            a0o = __builtin_amdgcn_mfma_f32_16x16x32_bf16(
                as_bf16x8(awh0[kk + 1]), hb[kk + 1], a0o, 0, 0, 0);
            a1o = __builtin_amdgcn_mfma_f32_16x16x32_bf16(
                as_bf16x8(awh1[kk + 1]), hb[kk + 1], a1o, 0, 0, 0);
        }
        const f32x4 acc0 = a0e + a0o;
        const f32x4 acc1 = a1e + a1o;

        // ---- activations (own 8 lcols: acc0 -> lcol=quad*4+r, acc1 -> +16) ----
        float v0[4], v1[4];
#pragma unroll
        for (int r = 0; r < 4; ++r) {
            const float p0 = acc0[r] + (float)gx[r];
            const float p1 = acc1[r] + (float)gx[4 + r];
            v0[r] = sigmoid_fast(p0);                              // F or I
            v1[r] = (quad < 2) ? tanh_fast(p1) : sigmoid_fast(p1); // A or O
        }
        // ---- exchange with quad^2 partner (lane ^ 32) ----
        float u0[4], u1[4];
#pragma unroll
        for (int r = 0; r < 4; ++r) {
            u0[r] = __shfl_xor(v0[r], 32, 64);
            u1[r] = __shfl_xor(v1[r], 32, 64);
        }
        const int rsel = 2 * (quad >> 1);
        const float f0 = (quad < 2) ? v0[rsel]     : u0[rsel];
        const float i0 = (quad < 2) ? u0[rsel]     : v0[rsel];
        const float a0 = (quad < 2) ? v1[rsel]     : u1[rsel];
        const float o0 = (quad < 2) ? u1[rsel]     : v1[rsel];
        const float f1 = (quad < 2) ? v0[rsel + 1] : u0[rsel + 1];
        const float i1 = (quad < 2) ? u0[rsel + 1] : v0[rsel + 1];
        const float a1 = (quad < 2) ? v1[rsel + 1] : u1[rsel + 1];
        const float o1 = (quad < 2) ? u1[rsel + 1] : v1[rsel + 1];

        const float cn0 = f0 * c0 + i0 * a0;  c0 = cn0;
        const float cn1 = f1 * c1 + i1 * a1;  c1 = cn1;
        const float h0 = o0 * tanh_fast(cn0);
        const float h1 = o1 * tanh_fast(cn1);

        const int hidx = b * HD_ + blk * UPB + jl0;
        if (t < T_ - 1) {
            // publish h first: drain covers ONLY this one MALL store ack.
            const unsigned int packed =
                (unsigned int)bf16_bits(h0) | ((unsigned int)bf16_bits(h1) << 16);
            *reinterpret_cast<volatile unsigned int*>(hout + hidx) = packed;
            __asm__ __volatile__("s_waitcnt vmcnt(0)" ::: "memory");
            if (lane == 0)
                *reinterpret_cast<volatile int*>(flags + (w << 7) + blk) = t + 1;
            __asm__ __volatile__("" ::: "memory");
            // prefetch next step's gx now: a full step of latency to hide,
            // and it is never caught by a pre-flag drain.
            gx_next = *reinterpret_cast<const bf16x8*>(
                gates3 + (((size_t)(t + 1) * NBLK + blk) * 256 + tid) * 8);
        }
        // out stores off the inter-block critical path (after flag publish)
        *reinterpret_cast<float2*>(
            out + ((size_t)b * T_ + t) * HD_ + blk * UPB + jl0) =
            make_float2(h0, h1);
        if (t == T_ - 1) {
            *reinterpret_cast<float2*>(out + (size_t)M1_ * HD_ + hidx) =
                make_float2(h0, h1);
            *reinterpret_cast<float2*>(
                out + (size_t)M1_ * HD_ + B_ * HD_ + hidx) =
                make_float2(cn0, cn1);
        }
    }
}

// -------------------------------------------------------------- launcher ----
extern "C" void kernel_launch(void* const* d_in, const int* in_sizes, int n_in,
                              void* d_out, int out_size, void* d_ws, size_t ws_size,
                              hipStream_t stream) {
    const float* x  = (const float*)d_in[0];
    const float* Wi = (const float*)d_in[1];
    const float* bi = (const float*)d_in[2];
    const float* Wh = (const float*)d_in[3];
    const float* bh = (const float*)d_in[4];
    float* out = (float*)d_out;

    char* ws = (char*)d_ws;
    size_t off = 0;
    bf16* xb     = (bf16*)(ws + off); off += (size_t)M1_ * ID_ * 2;       // 16 MB
    bf16* wiT    = (bf16*)(ws + off); off += (size_t)NG_ * ID_ * 2;       // 4 MB
    bf16* whT    = (bf16*)(ws + off); off += (size_t)NG_ * HD_ * 2;       // 8 MB
    bf16* gates3 = (bf16*)(ws + off); off += (size_t)T_ * B_ * NG_ * 2;   // 128 MB
    bf16* hbuf   = (bf16*)(ws + off); off += (size_t)2 * B_ * HD_ * 2;    // 256 KB
    int* flags   = (int*)(ws + off);  off += (size_t)NBLK * 4 * 16 * 4;   // 32 KB

    prep_kernel<<<8192, 256, 0, stream>>>(x, Wi, Wh, xb, wiT, whT, hbuf, flags);
    gates_gemm_kernel<<<dim3(128, 32), 256, 0, stream>>>(xb, wiT, bi, bh, gates3);

    lstm_persistent_kernel<<<dim3(NBLK), dim3(256), 0, stream>>>(
        gates3, whT, hbuf, out, flags);
}